// Round 5
// baseline (129.345 us; speedup 1.0000x reference)
//
#include <hip/hip_runtime.h>
#include <hip/hip_bf16.h>

// Problem constants (B=8, S=512, D=256, M=64, DE=256, H=8, DH=32).
// entity_mask == 0 always (softmax rows sum to 1 -> activity = 1/512 < 0.1),
// so graph output is exactly zero; only `entities` needs compute.
//
// Round 5: collapse 8 dispatches -> 4:
//   P: fused preproc (add_pos+split, wkv cvt, wo cvt, qproj, zero tail)
//   B: split-bf16 MFMA GEMM  K|V = x @ [wk|wv]      (grid 32x8, N=512)
//   C: fused attention (online softmax + LDS combine) -> ctx as bf16 hi/lo
//   D: split-bf16 MFMA GEMM  entities = ctx @ wo     (grid 4x4,  N=256)

typedef unsigned short ushort_t;
typedef __attribute__((ext_vector_type(8))) short short8;
typedef __attribute__((ext_vector_type(4))) float f32x4;

__device__ __forceinline__ ushort_t f2bf(float f) {
    unsigned u = __builtin_bit_cast(unsigned, f);
    unsigned r = (u + 0x7fff + ((u >> 16) & 1)) >> 16;   // RNE
    return (ushort_t)r;
}
__device__ __forceinline__ float bf2f(ushort_t h) {
    return __builtin_bit_cast(float, (unsigned)h << 16);
}

// ---------------- P: fused preprocessing ----------------
// blocks [0,1024):   x = emb+pos -> xh/xl        (262144 float4 items)
// blocks [1024,1536): wk|wv -> bh/bl [256x512]   (131072 items)
// blocks [1536,1792): wo -> wh/wl [256x256]      (65536 items)
// blocks [1792,1856): qproj (64 blocks, one m each)
// blocks [1856,1889): zero graph+mask tail of d_out (8320 float4)
__global__ __launch_bounds__(256) void preproc_kernel(
        const float* __restrict__ emb, const float* __restrict__ pos,
        const float* __restrict__ wk, const float* __restrict__ wv,
        const float* __restrict__ wo, const float* __restrict__ lib,
        const float* __restrict__ wq,
        ushort_t* __restrict__ xh, ushort_t* __restrict__ xl,
        ushort_t* __restrict__ bh, ushort_t* __restrict__ bl,
        ushort_t* __restrict__ wh, ushort_t* __restrict__ wl,
        float* __restrict__ qbuf, float4* __restrict__ tail) {
    __shared__ float sh[256];
    const int blk = blockIdx.x, tid = threadIdx.x;
    if (blk < 1024) {
        int i = blk * 256 + tid;
        int dq = i & 63, s = (i >> 6) & 511;
        float4 e = ((const float4*)emb)[i];
        float4 p = ((const float4*)pos)[(s << 6) + dq];
        float v[4] = {e.x + p.x, e.y + p.y, e.z + p.z, e.w + p.w};
        ushort_t h0 = f2bf(v[0]), h1 = f2bf(v[1]), h2 = f2bf(v[2]), h3 = f2bf(v[3]);
        ushort_t l0 = f2bf(v[0] - bf2f(h0)), l1 = f2bf(v[1] - bf2f(h1));
        ushort_t l2 = f2bf(v[2] - bf2f(h2)), l3 = f2bf(v[3] - bf2f(h3));
        ((uint2*)xh)[i] = make_uint2((unsigned)h0 | ((unsigned)h1 << 16),
                                     (unsigned)h2 | ((unsigned)h3 << 16));
        ((uint2*)xl)[i] = make_uint2((unsigned)l0 | ((unsigned)l1 << 16),
                                     (unsigned)l2 | ((unsigned)l3 << 16));
    } else if (blk < 1536) {
        int idx = (blk - 1024) * 256 + tid;          // 131072
        int row = idx >> 9, col = idx & 511;
        float v = (col < 256) ? wk[row * 256 + col] : wv[row * 256 + col - 256];
        ushort_t h = f2bf(v);
        bh[idx] = h;
        bl[idx] = f2bf(v - bf2f(h));
    } else if (blk < 1792) {
        int idx = (blk - 1536) * 256 + tid;          // 65536
        float v = wo[idx];
        ushort_t h = f2bf(v);
        wh[idx] = h;
        wl[idx] = f2bf(v - bf2f(h));
    } else if (blk < 1856) {
        int m = blk - 1792;
        sh[tid] = lib[m * 256 + tid];
        __syncthreads();
        float acc = 0.f;
        #pragma unroll 8
        for (int d = 0; d < 256; ++d) acc = fmaf(sh[d], wq[d * 256 + tid], acc);
        qbuf[m * 256 + tid] = acc * 0.17677669529663687f;   // 1/sqrt(32)
    } else {
        int i = (blk - 1856) * 256 + tid;
        if (i < 8320) tail[i] = make_float4(0.f, 0.f, 0.f, 0.f);
    }
}

// ---------------- generic split-bf16 MFMA GEMM ----------------
// C[*,N] (fp32, ldc=256 with col split at 256) = A[*,256] @ B[256,N],
// 3 split terms: Ah*Bh + Al*Bh + Ah*Bl. BM=128, BN=64, BK=32; 4 waves (2x2).
// cols [0,256) -> out0, [256,512) -> out1 (col-256).
__global__ __launch_bounds__(256) void gemm_split_mfma_kernel(
        const ushort_t* __restrict__ Ah, const ushort_t* __restrict__ Al,
        const ushort_t* __restrict__ Bh, const ushort_t* __restrict__ Bl,
        float* __restrict__ out0, float* __restrict__ out1, int N) {
    __shared__ ushort_t As[128][40];   // [m][k] +8 pad
    __shared__ ushort_t Bs[64][40];    // [n][k]
    const int tid = threadIdx.x;
    const int w = tid >> 6, l = tid & 63;
    const int wr = w >> 1, wc = w & 1;
    const int m0 = blockIdx.x * 128;
    const int n0 = blockIdx.y * 64;
    const int l15 = l & 15, lk8 = (l >> 4) * 8;

    const ushort_t* Aseg[3] = {Ah, Al, Ah};
    const ushort_t* Bseg[3] = {Bh, Bh, Bl};

    f32x4 acc[4][2];
    #pragma unroll
    for (int i = 0; i < 4; ++i)
        #pragma unroll
        for (int j = 0; j < 2; ++j) acc[i][j] = (f32x4){0.f, 0.f, 0.f, 0.f};

    const int ar = tid >> 1, ah = (tid & 1) * 16;  // A: row, 16-ushort half
    const int bn = tid & 63, bk = tid >> 6;        // B: col, k-block of 8

    short8 areg0, areg1;
    ushort_t breg[8];
    #define PRELOAD(st) do { \
        int seg = (st) >> 3, k0 = ((st) & 7) << 5; \
        const ushort_t* Ap = Aseg[seg] + (size_t)(m0 + ar) * 256 + k0 + ah; \
        areg0 = *(const short8*)Ap; \
        areg1 = *(const short8*)(Ap + 8); \
        const ushort_t* Bp = Bseg[seg] + (size_t)(k0 + bk * 8) * N + n0 + bn; \
        _Pragma("unroll") \
        for (int j = 0; j < 8; ++j) breg[j] = Bp[(size_t)j * N]; \
    } while (0)

    PRELOAD(0);
    for (int st = 0; st < 24; ++st) {
        __syncthreads();
        *(short8*)&As[ar][ah]     = areg0;
        *(short8*)&As[ar][ah + 8] = areg1;
        {
            short8 bv;
            #pragma unroll
            for (int j = 0; j < 8; ++j) bv[j] = (short)breg[j];
            *(short8*)&Bs[bn][bk * 8] = bv;
        }
        __syncthreads();
        if (st + 1 < 24) PRELOAD(st + 1);
        short8 a[4], b[2];
        #pragma unroll
        for (int i = 0; i < 4; ++i) a[i] = *(const short8*)&As[wr * 64 + i * 16 + l15][lk8];
        #pragma unroll
        for (int j = 0; j < 2; ++j) b[j] = *(const short8*)&Bs[wc * 32 + j * 16 + l15][lk8];
        #pragma unroll
        for (int i = 0; i < 4; ++i)
            #pragma unroll
            for (int j = 0; j < 2; ++j)
                acc[i][j] = __builtin_amdgcn_mfma_f32_16x16x32_bf16(a[i], b[j], acc[i][j], 0, 0, 0);
    }
    #undef PRELOAD

    // C/D layout: col=lane&15, row=(lane>>4)*4+reg [m89-verified]
    float* outp = (n0 < 256) ? out0 : out1;
    const int nbase = (n0 < 256) ? n0 : (n0 - 256);
    #pragma unroll
    for (int i = 0; i < 4; ++i) {
        #pragma unroll
        for (int j = 0; j < 2; ++j) {
            int col = nbase + wc * 32 + j * 16 + l15;
            int rowb = m0 + wr * 64 + i * 16 + (l >> 4) * 4;
            #pragma unroll
            for (int r = 0; r < 4; ++r)
                outp[(size_t)(rowb + r) * 256 + col] = acc[i][j][r];
        }
    }
}

// ---------------- C: fused attention -> ctx bf16 hi/lo ----------------
// grid 64 = (b,h); 256 threads = 4 waves; wave w covers s in [w*128,(w+1)*128).
// lane = query m. Online softmax per wave; cross-wave combine in LDS.
__global__ __launch_bounds__(256) void attn_fused_kernel(const float* __restrict__ q,
        const float* __restrict__ k, const float* __restrict__ v,
        ushort_t* __restrict__ ch, ushort_t* __restrict__ cl) {
    __shared__ float sM[4][64], sS[4][64];
    __shared__ float sAcc[4][64][36];     // +4 pad: float4-aligned, 8-way max alias
    const int bhid = blockIdx.x;
    const int b = bhid >> 3, h = bhid & 7;
    const int w = threadIdx.x >> 6;
    const int m = threadIdx.x & 63;
    const int s0 = w * 128;

    float qr[32];
    {
        const float4* qp = (const float4*)(q + m * 256 + h * 32);
        #pragma unroll
        for (int u = 0; u < 8; ++u) {
            float4 t = qp[u];
            qr[4*u] = t.x; qr[4*u+1] = t.y; qr[4*u+2] = t.z; qr[4*u+3] = t.w;
        }
    }
    const float* kbase = k + ((size_t)(b * 512 + s0)) * 256 + h * 32;
    const float* vbase = v + ((size_t)(b * 512 + s0)) * 256 + h * 32;

    float Mx = -1e30f, sum = 0.f, acc[32];
    #pragma unroll
    for (int dh = 0; dh < 32; ++dh) acc[dh] = 0.f;

    for (int cc = 0; cc < 16; ++cc) {          // 16 chunks x 8 s-rows = 128
        float sc[8];
        #pragma unroll
        for (int i = 0; i < 8; ++i) {
            const float4* kr = (const float4*)(kbase + (size_t)(cc * 8 + i) * 256);
            float dsum = 0.f;
            #pragma unroll
            for (int u = 0; u < 8; ++u) {
                float4 kv = kr[u];
                dsum = fmaf(qr[4*u],   kv.x, dsum);
                dsum = fmaf(qr[4*u+1], kv.y, dsum);
                dsum = fmaf(qr[4*u+2], kv.z, dsum);
                dsum = fmaf(qr[4*u+3], kv.w, dsum);
            }
            sc[i] = dsum;
        }
        float cm = sc[0];
        #pragma unroll
        for (int i = 1; i < 8; ++i) cm = fmaxf(cm, sc[i]);
        float nm = fmaxf(Mx, cm);
        float f = __expf(Mx - nm);
        sum *= f;
        #pragma unroll
        for (int dh = 0; dh < 32; ++dh) acc[dh] *= f;
        #pragma unroll
        for (int i = 0; i < 8; ++i) {
            float p = __expf(sc[i] - nm);
            sum += p;
            const float4* vr = (const float4*)(vbase + (size_t)(cc * 8 + i) * 256);
            #pragma unroll
            for (int u = 0; u < 8; ++u) {
                float4 vv = vr[u];
                acc[4*u]   = fmaf(p, vv.x, acc[4*u]);
                acc[4*u+1] = fmaf(p, vv.y, acc[4*u+1]);
                acc[4*u+2] = fmaf(p, vv.z, acc[4*u+2]);
                acc[4*u+3] = fmaf(p, vv.w, acc[4*u+3]);
            }
        }
        Mx = nm;
    }

    sM[w][m] = Mx; sS[w][m] = sum;
    #pragma unroll
    for (int u = 0; u < 8; ++u)
        *(float4*)&sAcc[w][m][4*u] = make_float4(acc[4*u], acc[4*u+1], acc[4*u+2], acc[4*u+3]);
    __syncthreads();

    // combine: thread t -> (mm = t>>2, g = t&3) handles 8 dh values
    const int t = threadIdx.x;
    const int mm = t >> 2, g = t & 3;
    float Mj[4], Sj[4];
    float Mg = -1e30f;
    #pragma unroll
    for (int j = 0; j < 4; ++j) { Mj[j] = sM[j][mm]; Mg = fmaxf(Mg, Mj[j]); }
    float wgt[4]; float Ssum = 0.f;
    #pragma unroll
    for (int j = 0; j < 4; ++j) { wgt[j] = __expf(Mj[j] - Mg); Ssum = fmaf(wgt[j], sS[j][mm], Ssum); }
    float inv = 1.f / Ssum;
    ushort_t hv[8], lv[8];
    #pragma unroll
    for (int u = 0; u < 8; ++u) {
        int dh = g * 8 + u;
        float num = 0.f;
        #pragma unroll
        for (int j = 0; j < 4; ++j) num = fmaf(wgt[j], sAcc[j][mm][dh], num);
        float val = num * inv;
        hv[u] = f2bf(val);
        lv[u] = f2bf(val - bf2f(hv[u]));
    }
    size_t off = ((size_t)(b * 64 + mm)) * 256 + h * 32 + g * 8;
    short8 hp, lp;
    #pragma unroll
    for (int u = 0; u < 8; ++u) { hp[u] = (short)hv[u]; lp[u] = (short)lv[u]; }
    *(short8*)(ch + off) = hp;
    *(short8*)(cl + off) = lp;
}

extern "C" void kernel_launch(void* const* d_in, const int* in_sizes, int n_in,
                              void* d_out, int out_size, void* d_ws, size_t ws_size,
                              hipStream_t stream) {
    const float* emb = (const float*)d_in[0];
    const float* lib = (const float*)d_in[2];
    const float* pos = (const float*)d_in[3];
    const float* wq  = (const float*)d_in[4];
    const float* wk  = (const float*)d_in[5];
    const float* wv  = (const float*)d_in[6];
    const float* wo  = (const float*)d_in[7];
    float* out = (float*)d_out;

    float* ws   = (float*)d_ws;
    float* kbuf = ws;                        // 1,048,576 f
    float* vbuf = kbuf + 1048576;            // 1,048,576 f
    float* qbuf = vbuf + 1048576;            // 16,384 f
    ushort_t* us = (ushort_t*)(qbuf + 16384);
    ushort_t* xh = us;                       // 1,048,576
    ushort_t* xl = xh + 1048576;             // 1,048,576
    ushort_t* bh = xl + 1048576;             // 131,072
    ushort_t* bl = bh + 131072;              // 131,072
    ushort_t* wh = bl + 131072;              // 65,536
    ushort_t* wl = wh + 65536;               // 65,536
    ushort_t* ch = wl + 65536;               // 131,072
    ushort_t* cl = ch + 131072;              // 131,072  (total ~14 MB)

    preproc_kernel<<<1889, 256, 0, stream>>>(emb, pos, wk, wv, wo, lib, wq,
            xh, xl, bh, bl, wh, wl, qbuf, (float4*)(out + 131072));

    gemm_split_mfma_kernel<<<dim3(32, 8), 256, 0, stream>>>(xh, xl, bh, bl, kbuf, vbuf, 512);

    attn_fused_kernel<<<64, 256, 0, stream>>>(qbuf, kbuf, vbuf, ch, cl);

    gemm_split_mfma_kernel<<<dim3(4, 4), 256, 0, stream>>>(ch, cl, wh, wl, out, out, 256);
}

// Round 6
// 64.733 us; speedup vs baseline: 1.9981x; 1.9981x over previous
//
#include <hip/hip_runtime.h>
#include <hip/hip_bf16.h>

// Problem constants (B=8, S=512, D=256, M=64, DE=256, H=8, DH=32).
// entity_mask == 0 always (softmax rows sum to 1 -> activity = 1/512 < 0.1),
// so graph output is exactly zero; only `entities` needs compute.
//
// Round 6: fix attention latency-bound regression (r5: 64 blocks, occupancy
// 2.7%, 79.7us). Now: 512 blocks, LDS-staged K/V, split accumulators,
// in-block 4-wave merge -> 8 partials/(bh,m) -> small combine kernel.

typedef unsigned short ushort_t;
typedef __attribute__((ext_vector_type(8))) short short8;
typedef __attribute__((ext_vector_type(4))) float f32x4;

__device__ __forceinline__ ushort_t f2bf(float f) {
    unsigned u = __builtin_bit_cast(unsigned, f);
    unsigned r = (u + 0x7fff + ((u >> 16) & 1)) >> 16;   // RNE
    return (ushort_t)r;
}
__device__ __forceinline__ float bf2f(ushort_t h) {
    return __builtin_bit_cast(float, (unsigned)h << 16);
}

// ---------------- P: fused preprocessing ----------------
__global__ __launch_bounds__(256) void preproc_kernel(
        const float* __restrict__ emb, const float* __restrict__ pos,
        const float* __restrict__ wk, const float* __restrict__ wv,
        const float* __restrict__ wo, const float* __restrict__ lib,
        const float* __restrict__ wq,
        ushort_t* __restrict__ xh, ushort_t* __restrict__ xl,
        ushort_t* __restrict__ bh, ushort_t* __restrict__ bl,
        ushort_t* __restrict__ wh, ushort_t* __restrict__ wl,
        float* __restrict__ qbuf, float4* __restrict__ tail) {
    __shared__ float sh[256];
    const int blk = blockIdx.x, tid = threadIdx.x;
    if (blk < 1024) {
        int i = blk * 256 + tid;
        int dq = i & 63, s = (i >> 6) & 511;
        float4 e = ((const float4*)emb)[i];
        float4 p = ((const float4*)pos)[(s << 6) + dq];
        float v[4] = {e.x + p.x, e.y + p.y, e.z + p.z, e.w + p.w};
        ushort_t h0 = f2bf(v[0]), h1 = f2bf(v[1]), h2 = f2bf(v[2]), h3 = f2bf(v[3]);
        ushort_t l0 = f2bf(v[0] - bf2f(h0)), l1 = f2bf(v[1] - bf2f(h1));
        ushort_t l2 = f2bf(v[2] - bf2f(h2)), l3 = f2bf(v[3] - bf2f(h3));
        ((uint2*)xh)[i] = make_uint2((unsigned)h0 | ((unsigned)h1 << 16),
                                     (unsigned)h2 | ((unsigned)h3 << 16));
        ((uint2*)xl)[i] = make_uint2((unsigned)l0 | ((unsigned)l1 << 16),
                                     (unsigned)l2 | ((unsigned)l3 << 16));
    } else if (blk < 1536) {
        int idx = (blk - 1024) * 256 + tid;          // 131072
        int row = idx >> 9, col = idx & 511;
        float v = (col < 256) ? wk[row * 256 + col] : wv[row * 256 + col - 256];
        ushort_t h = f2bf(v);
        bh[idx] = h;
        bl[idx] = f2bf(v - bf2f(h));
    } else if (blk < 1792) {
        int idx = (blk - 1536) * 256 + tid;          // 65536
        float v = wo[idx];
        ushort_t h = f2bf(v);
        wh[idx] = h;
        wl[idx] = f2bf(v - bf2f(h));
    } else if (blk < 1856) {
        int m = blk - 1792;
        sh[tid] = lib[m * 256 + tid];
        __syncthreads();
        float acc = 0.f;
        #pragma unroll 8
        for (int d = 0; d < 256; ++d) acc = fmaf(sh[d], wq[d * 256 + tid], acc);
        qbuf[m * 256 + tid] = acc * 0.17677669529663687f;   // 1/sqrt(32)
    } else {
        int i = (blk - 1856) * 256 + tid;
        if (i < 8320) tail[i] = make_float4(0.f, 0.f, 0.f, 0.f);
    }
}

// ---------------- generic split-bf16 MFMA GEMM ----------------
// C[*,N] = A[*,256] @ B[256,N]; 3 terms Ah*Bh + Al*Bh + Ah*Bl.
// BM=128, BN=64, BK=32; cols [0,256)->out0, [256,512)->out1.
__global__ __launch_bounds__(256) void gemm_split_mfma_kernel(
        const ushort_t* __restrict__ Ah, const ushort_t* __restrict__ Al,
        const ushort_t* __restrict__ Bh, const ushort_t* __restrict__ Bl,
        float* __restrict__ out0, float* __restrict__ out1, int N) {
    __shared__ ushort_t As[128][40];
    __shared__ ushort_t Bs[64][40];
    const int tid = threadIdx.x;
    const int w = tid >> 6, l = tid & 63;
    const int wr = w >> 1, wc = w & 1;
    const int m0 = blockIdx.x * 128;
    const int n0 = blockIdx.y * 64;
    const int l15 = l & 15, lk8 = (l >> 4) * 8;

    const ushort_t* Aseg[3] = {Ah, Al, Ah};
    const ushort_t* Bseg[3] = {Bh, Bh, Bl};

    f32x4 acc[4][2];
    #pragma unroll
    for (int i = 0; i < 4; ++i)
        #pragma unroll
        for (int j = 0; j < 2; ++j) acc[i][j] = (f32x4){0.f, 0.f, 0.f, 0.f};

    const int ar = tid >> 1, ah = (tid & 1) * 16;
    const int bn = tid & 63, bk = tid >> 6;

    short8 areg0, areg1;
    ushort_t breg[8];
    #define PRELOAD(st) do { \
        int seg = (st) >> 3, k0 = ((st) & 7) << 5; \
        const ushort_t* Ap = Aseg[seg] + (size_t)(m0 + ar) * 256 + k0 + ah; \
        areg0 = *(const short8*)Ap; \
        areg1 = *(const short8*)(Ap + 8); \
        const ushort_t* Bp = Bseg[seg] + (size_t)(k0 + bk * 8) * N + n0 + bn; \
        _Pragma("unroll") \
        for (int j = 0; j < 8; ++j) breg[j] = Bp[(size_t)j * N]; \
    } while (0)

    PRELOAD(0);
    for (int st = 0; st < 24; ++st) {
        __syncthreads();
        *(short8*)&As[ar][ah]     = areg0;
        *(short8*)&As[ar][ah + 8] = areg1;
        {
            short8 bv;
            #pragma unroll
            for (int j = 0; j < 8; ++j) bv[j] = (short)breg[j];
            *(short8*)&Bs[bn][bk * 8] = bv;
        }
        __syncthreads();
        if (st + 1 < 24) PRELOAD(st + 1);
        short8 a[4], b[2];
        #pragma unroll
        for (int i = 0; i < 4; ++i) a[i] = *(const short8*)&As[wr * 64 + i * 16 + l15][lk8];
        #pragma unroll
        for (int j = 0; j < 2; ++j) b[j] = *(const short8*)&Bs[wc * 32 + j * 16 + l15][lk8];
        #pragma unroll
        for (int i = 0; i < 4; ++i)
            #pragma unroll
            for (int j = 0; j < 2; ++j)
                acc[i][j] = __builtin_amdgcn_mfma_f32_16x16x32_bf16(a[i], b[j], acc[i][j], 0, 0, 0);
    }
    #undef PRELOAD

    float* outp = (n0 < 256) ? out0 : out1;
    const int nbase = (n0 < 256) ? n0 : (n0 - 256);
    #pragma unroll
    for (int i = 0; i < 4; ++i) {
        #pragma unroll
        for (int j = 0; j < 2; ++j) {
            int col = nbase + wc * 32 + j * 16 + l15;
            int rowb = m0 + wr * 64 + i * 16 + (l >> 4) * 4;
            #pragma unroll
            for (int r = 0; r < 4; ++r)
                outp[(size_t)(rowb + r) * 256 + col] = acc[i][j][r];
        }
    }
}

// ---------------- attention partials with LDS-staged K/V ----------------
// grid (64 bh, 8 sq); block covers 64 s-rows; 4 waves x 16 rows; lane = m.
// Stage K/V slice (16KB) coalesced; compute from LDS; in-block 4-wave merge
// (LDS aliased with staging, barrier-separated) -> one partial per (bh,sq,m).
__global__ __launch_bounds__(256) void attn_stage_kernel(const float* __restrict__ q,
        const float* __restrict__ k, const float* __restrict__ v,
        float* __restrict__ part) {
    __shared__ float sM[4][64], sS[4][64];
    __shared__ __align__(16) float big[9216];   // 36KB: stage 4096f | merge 4*64*36
    const int bh = blockIdx.x, sq = blockIdx.y;
    const int b = bh >> 3, h = bh & 7;
    const int tid = threadIdx.x;
    const int w = tid >> 6, m = tid & 63;
    const int s0b = sq * 64;

    // ---- stage K,V: 64 rows x 32 floats each, fully coalesced ----
    {
        float4* Ks4 = (float4*)big;             // 512 float4
        float4* Vs4 = Ks4 + 512;
        #pragma unroll
        for (int it = 0; it < 2; ++it) {
            int idx = it * 256 + tid;           // 0..511
            int row = idx >> 3, f4 = idx & 7;
            const float* kb = k + (size_t)(b * 512 + s0b + row) * 256 + h * 32;
            const float* vb = v + (size_t)(b * 512 + s0b + row) * 256 + h * 32;
            Ks4[idx] = ((const float4*)kb)[f4];
            Vs4[idx] = ((const float4*)vb)[f4];
        }
    }

    float qr[32];
    {
        const float4* qp = (const float4*)(q + m * 256 + h * 32);
        #pragma unroll
        for (int u = 0; u < 8; ++u) {
            float4 t4 = qp[u];
            qr[4*u] = t4.x; qr[4*u+1] = t4.y; qr[4*u+2] = t4.z; qr[4*u+3] = t4.w;
        }
    }
    __syncthreads();

    const float* Ks = big;          // [64][32]
    const float* Vs = big + 2048;   // [64][32]
    float Mx = -1e30f, sum = 0.f, acc[32];
    #pragma unroll
    for (int dh = 0; dh < 32; ++dh) acc[dh] = 0.f;

    #pragma unroll
    for (int cc = 0; cc < 2; ++cc) {            // 2 chunks x 8 rows = 16 rows/wave
        float sc[8];
        #pragma unroll
        for (int i = 0; i < 8; ++i) {
            const float4* kr = (const float4*)&Ks[(size_t)(w * 16 + cc * 8 + i) * 32];
            float d0 = 0.f, d1 = 0.f, d2 = 0.f, d3 = 0.f;
            #pragma unroll
            for (int u = 0; u < 8; ++u) {
                float4 kv = kr[u];
                d0 = fmaf(qr[4*u],   kv.x, d0);
                d1 = fmaf(qr[4*u+1], kv.y, d1);
                d2 = fmaf(qr[4*u+2], kv.z, d2);
                d3 = fmaf(qr[4*u+3], kv.w, d3);
            }
            sc[i] = (d0 + d1) + (d2 + d3);
        }
        float cm = sc[0];
        #pragma unroll
        for (int i = 1; i < 8; ++i) cm = fmaxf(cm, sc[i]);
        float nm = fmaxf(Mx, cm);
        float f = __expf(Mx - nm);
        sum *= f;
        #pragma unroll
        for (int dh = 0; dh < 32; ++dh) acc[dh] *= f;
        #pragma unroll
        for (int i = 0; i < 8; ++i) {
            float p = __expf(sc[i] - nm);
            sum += p;
            const float4* vr = (const float4*)&Vs[(size_t)(w * 16 + cc * 8 + i) * 32];
            #pragma unroll
            for (int u = 0; u < 8; ++u) {
                float4 vv = vr[u];
                acc[4*u]   = fmaf(p, vv.x, acc[4*u]);
                acc[4*u+1] = fmaf(p, vv.y, acc[4*u+1]);
                acc[4*u+2] = fmaf(p, vv.z, acc[4*u+2]);
                acc[4*u+3] = fmaf(p, vv.w, acc[4*u+3]);
            }
        }
        Mx = nm;
    }
    __syncthreads();    // all waves done reading Ks/Vs; big is reusable

    // ---- in-block merge of 4 waves ----
    sM[w][m] = Mx; sS[w][m] = sum;
    float* sAcc = big;  // [4][64][36] (stride 36 -> 144B rows, float4-aligned)
    #pragma unroll
    for (int u = 0; u < 8; ++u)
        *(float4*)&sAcc[(size_t)(w * 64 + m) * 36 + 4 * u] =
            make_float4(acc[4*u], acc[4*u+1], acc[4*u+2], acc[4*u+3]);
    __syncthreads();

    const int mm = tid >> 2, g = tid & 3;
    float Mj[4];
    float Mg = -1e30f;
    #pragma unroll
    for (int j = 0; j < 4; ++j) { Mj[j] = sM[j][mm]; Mg = fmaxf(Mg, Mj[j]); }
    float wgt[4]; float Ssum = 0.f;
    #pragma unroll
    for (int j = 0; j < 4; ++j) { wgt[j] = __expf(Mj[j] - Mg); Ssum = fmaf(wgt[j], sS[j][mm], Ssum); }
    float* rec = part + ((size_t)(bh * 8 + sq) * 64 + mm) * 36;
    #pragma unroll
    for (int uq = 0; uq < 2; ++uq) {
        float o[4];
        #pragma unroll
        for (int u = 0; u < 4; ++u) {
            int dh = g * 8 + uq * 4 + u;
            float num = 0.f;
            #pragma unroll
            for (int j = 0; j < 4; ++j) num = fmaf(wgt[j], sAcc[(size_t)(j * 64 + mm) * 36 + dh], num);
            o[u] = num;
        }
        *(float4*)(rec + g * 8 + uq * 4) = make_float4(o[0], o[1], o[2], o[3]);
    }
    if (g == 0) { rec[32] = Mg; rec[33] = Ssum; }
}

// ---------------- combine 8 partials -> ctx bf16 hi/lo ----------------
__global__ __launch_bounds__(256) void attn_combine8_kernel(const float* __restrict__ part,
        ushort_t* __restrict__ ch, ushort_t* __restrict__ cl) {
    const int bh = blockIdx.x;
    const int b = bh >> 3, h = bh & 7;
    const int t = threadIdx.x;
    const int mm = t >> 2, g = t & 3;
    const float* pb = part + ((size_t)(bh * 8) * 64 + mm) * 36;
    float Mj[8], Sj[8];
    float Mg = -1e30f;
    #pragma unroll
    for (int j = 0; j < 8; ++j) {
        Mj[j] = pb[(size_t)j * 64 * 36 + 32];
        Sj[j] = pb[(size_t)j * 64 * 36 + 33];
        Mg = fmaxf(Mg, Mj[j]);
    }
    float wgt[8]; float Ssum = 0.f;
    #pragma unroll
    for (int j = 0; j < 8; ++j) { wgt[j] = __expf(Mj[j] - Mg); Ssum = fmaf(wgt[j], Sj[j], Ssum); }
    float inv = 1.f / Ssum;
    short8 hp, lp;
    #pragma unroll
    for (int u = 0; u < 8; ++u) {
        int dh = g * 8 + u;
        float num = 0.f;
        #pragma unroll
        for (int j = 0; j < 8; ++j) num = fmaf(wgt[j], pb[(size_t)j * 64 * 36 + dh], num);
        float val = num * inv;
        ushort_t hv = f2bf(val);
        hp[u] = (short)hv;
        lp[u] = (short)f2bf(val - bf2f(hv));
    }
    size_t off = ((size_t)(b * 64 + mm)) * 256 + h * 32 + g * 8;
    *(short8*)(ch + off) = hp;
    *(short8*)(cl + off) = lp;
}

extern "C" void kernel_launch(void* const* d_in, const int* in_sizes, int n_in,
                              void* d_out, int out_size, void* d_ws, size_t ws_size,
                              hipStream_t stream) {
    const float* emb = (const float*)d_in[0];
    const float* lib = (const float*)d_in[2];
    const float* pos = (const float*)d_in[3];
    const float* wq  = (const float*)d_in[4];
    const float* wk  = (const float*)d_in[5];
    const float* wv  = (const float*)d_in[6];
    const float* wo  = (const float*)d_in[7];
    float* out = (float*)d_out;

    float* ws   = (float*)d_ws;
    float* kbuf = ws;                        // 1,048,576 f
    float* vbuf = kbuf + 1048576;            // 1,048,576 f
    float* qbuf = vbuf + 1048576;            // 16,384 f
    ushort_t* xh = (ushort_t*)(qbuf + 16384);// 1,048,576 us
    ushort_t* xl = xh + 1048576;             // 1,048,576 us
    ushort_t* bh = xl + 1048576;             // 131,072 us
    ushort_t* bl = bh + 131072;              // 131,072 us
    ushort_t* wh = bl + 131072;              // 65,536 us
    ushort_t* wl = wh + 65536;               // 65,536 us
    ushort_t* ch = wl + 65536;               // 131,072 us
    ushort_t* cl = ch + 131072;              // 131,072 us
    // part [64bh][8sq][64m][36] = 1,179,648 f aliases xh..bl (dead after KV GEMM)
    float* part = (float*)xh;

    preproc_kernel<<<1889, 256, 0, stream>>>(emb, pos, wk, wv, wo, lib, wq,
            xh, xl, bh, bl, wh, wl, qbuf, (float4*)(out + 131072));

    gemm_split_mfma_kernel<<<dim3(32, 8), 256, 0, stream>>>(xh, xl, bh, bl, kbuf, vbuf, 512);

    attn_stage_kernel<<<dim3(64, 8), 256, 0, stream>>>(qbuf, kbuf, vbuf, part);
    attn_combine8_kernel<<<64, 256, 0, stream>>>(part, ch, cl);

    gemm_split_mfma_kernel<<<dim3(4, 4), 256, 0, stream>>>(ch, cl, wh, wl, out, out, 256);
}